// Round 2
// baseline (358.481 us; speedup 1.0000x reference)
//
#include <hip/hip_runtime.h>

// XY model log-density: out[b] = sum_s [cos(th[up(s)]-th[s]) + cos(th[right(s)]-th[s])]
// 64x64 periodic lattice; up(s)=(s+64)&4095, right(s)=s+1 within the x-row (wrap -63).
// Memory-bound: 256 MiB input, ~43 us floor at 6.3 TB/s achievable.
//
// Structure: 2048 blocks x 256 threads, 8 samples per block, double-buffered LDS.
// Prefetch for sample i+1 is issued AFTER the barrier that publishes sample i, so the
// barrier's vmcnt(0) drain always waits on a load that had a full compute window in
// flight. Staging uses global_load_lds width=16 (no VGPR round trip); the per-wave
// LDS destination is contiguous, matching the wave-uniform-base + lane*16 semantics.

#define LAT_L    64
#define NSITE    4096
#define BLOCK    256
#define NSAMPLE  16384
#define SPB      8                    // samples per block
#define NBLK     (NSAMPLE / SPB)      // 2048

typedef float f4 __attribute__((ext_vector_type(4)));

__device__ __forceinline__ void prefetch_row(const float* __restrict__ grow,
                                             float* lbuf, int t) {
    const int w = t >> 6;   // wave id (wave-uniform)
    const int l = t & 63;
    const f4* __restrict__ g4 = (const f4*)grow;
    f4* l4 = (f4*)lbuf;
#pragma unroll
    for (int k = 0; k < 4; ++k) {
        const int base = w * 64 + 256 * k;  // float4 units; wave-uniform
        const __attribute__((address_space(1))) void* gp =
            (const __attribute__((address_space(1))) void*)(g4 + base + l);
        __attribute__((address_space(3))) void* lp =
            (__attribute__((address_space(3))) void*)(l4 + base);
        __builtin_amdgcn_global_load_lds(gp, lp, 16, 0, 0);
    }
}

__device__ __forceinline__ float compute_row(const float* __restrict__ th,
                                             int t, int rdelta) {
    float s0 = 0.0f, s1 = 0.0f;
#pragma unroll
    for (int k = 0; k < NSITE / BLOCK; ++k) {   // 16 sites, stride 256: conflict-free b32
        const int s = t + BLOCK * k;
        const float ts = th[s];
        const float tu = th[(s + LAT_L) & (NSITE - 1)];
        const float tr = th[s + rdelta];
        s0 += __cosf(tu - ts);
        s1 += __cosf(tr - ts);
    }
    return s0 + s1;
}

__global__ __launch_bounds__(BLOCK)
void xy_logdensity_kernel(const float* __restrict__ state, float* __restrict__ out) {
    __shared__ float buf[2][NSITE];   // 32 KiB double buffer
    __shared__ float red[2][BLOCK / 64];

    const int t = threadIdx.x;
    const long base_sample = (long)blockIdx.x * SPB;
    // right neighbor: +1 within the 64-site x-row, wrap to -63 at x==63.
    // site s = t + 256k => x = t & 63 (k-independent), so rdelta is per-thread constant.
    const int rdelta = ((t & 63) == (LAT_L - 1)) ? -(LAT_L - 1) : 1;

    prefetch_row(state + base_sample * NSITE, buf[0], t);

    for (int i = 0; i < SPB; ++i) {
        __syncthreads();   // drains vmcnt: prefetch(i) complete; red[(i-1)&1] visible
        if (i > 0 && t == 0) {
            const float* r = red[(i - 1) & 1];
            out[base_sample + i - 1] = r[0] + r[1] + r[2] + r[3];
        }
        if (i + 1 < SPB)
            prefetch_row(state + (base_sample + i + 1) * NSITE, buf[(i + 1) & 1], t);

        float sum = compute_row(buf[i & 1], t, rdelta);   // overlaps prefetch(i+1)

#pragma unroll
        for (int off = 32; off > 0; off >>= 1)
            sum += __shfl_down(sum, off, 64);
        if ((t & 63) == 0) red[i & 1][t >> 6] = sum;
    }
    __syncthreads();
    if (t == 0) {
        const float* r = red[(SPB - 1) & 1];
        out[base_sample + SPB - 1] = r[0] + r[1] + r[2] + r[3];
    }
}

extern "C" void kernel_launch(void* const* d_in, const int* in_sizes, int n_in,
                              void* d_out, int out_size, void* d_ws, size_t ws_size,
                              hipStream_t stream) {
    const float* state = (const float*)d_in[0];
    // d_in[1] (int64 shift table) is the deterministic 64x64 periodic roll;
    // computed in-register instead of gathered.
    float* out = (float*)d_out;

    xy_logdensity_kernel<<<NBLK, BLOCK, 0, stream>>>(state, out);
}